// Round 21
// baseline (232.824 us; speedup 1.0000x reference)
//
#include <hip/hip_runtime.h>

#define TSEQ 1024
#define HID_ 1024
#define NH 8
#define DK 128
#define DV 128
#define ROWS 2048               // B*T
#define SZf (ROWS * HID_)       // elements per [2048,1024] matrix
#define LCH 64                  // scan chunk length
#define NCK 16                  // chunks per (b,h)
#define KSTR 136                // bf16 LDS stride
#define ESTR 68                 // f32 LDS stride (16B-aligned rows for b128 bcast)

typedef __attribute__((ext_vector_type(8))) short short8;
typedef __attribute__((ext_vector_type(4))) float f32x4;
#define MFMA __builtin_amdgcn_mfma_f32_16x16x32_bf16

__device__ __forceinline__ float sig_(float x) { return 1.f / (1.f + __expf(-x)); }

__device__ __forceinline__ ushort f2bf(float f) {   // RNE f32->bf16
    unsigned int u = __builtin_bit_cast(unsigned int, f);
    u += 0x7FFF + ((u >> 16) & 1);
    return (ushort)(u >> 16);
}
__device__ __forceinline__ float bf2f(ushort u) {
    return __builtin_bit_cast(float, ((unsigned int)u) << 16);
}
__device__ __forceinline__ unsigned int pk2(float lo, float hi) {
    return (unsigned int)f2bf(lo) | ((unsigned int)f2bf(hi) << 16);
}

// async global->LDS, 16B per lane; dst = wave-uniform base (+lane*16 by HW)
__device__ __forceinline__ void gload16(const void* g, void* l) {
    __builtin_amdgcn_global_load_lds(
        (const __attribute__((address_space(1))) unsigned int*)g,
        (__attribute__((address_space(3))) unsigned int*)l, 16, 0, 0);
}

// ---------------- x -> bf16 ----------------
__global__ __launch_bounds__(256)
void k_x2bf(const float* __restrict__ x, ushort* __restrict__ xb)
{
    const size_t i8 = (size_t)blockIdx.x * 256 + threadIdx.x;   // grid 1024
    float4 v0 = *(const float4*)(x + i8 * 8);
    float4 v1 = *(const float4*)(x + i8 * 8 + 4);
    uint4 o;
    o.x = pk2(v0.x, v0.y); o.y = pk2(v0.z, v0.w);
    o.z = pk2(v1.x, v1.y); o.w = pk2(v1.z, v1.w);
    *(uint4*)(xb + i8 * 8) = o;
}

// -------- weight transpose+convert: W f32 [K][N] -> WT bf16 [N][K]; z=4 -> Wo
__global__ __launch_bounds__(256)
void k_wT(const float* __restrict__ s0, const float* __restrict__ s1,
          const float* __restrict__ s2, const float* __restrict__ s3,
          const float* __restrict__ s4,
          ushort* __restrict__ dst, ushort* __restrict__ dstWo)
{
    const int z = blockIdx.z;
    const float* W = (z == 0) ? s0 : (z == 1) ? s1 : (z == 2) ? s2
                   : (z == 3) ? s3 : s4;
    ushort* WT = (z < 4) ? dst + (size_t)z * (1024 * 1024) : dstWo;
    __shared__ float t[64][65];
    const int n0 = blockIdx.x * 64, k0 = blockIdx.y * 64;
    const int rr = threadIdx.x >> 4, cc = threadIdx.x & 15;
#pragma unroll
    for (int i = 0; i < 4; ++i) {
        const int row = i * 16 + rr;
        float4 v = *(const float4*)(W + (size_t)(k0 + row) * 1024 + n0 + cc * 4);
        t[row][cc * 4 + 0] = v.x; t[row][cc * 4 + 1] = v.y;
        t[row][cc * 4 + 2] = v.z; t[row][cc * 4 + 3] = v.w;
    }
    __syncthreads();
#pragma unroll
    for (int i = 0; i < 4; ++i) {
        const int n = i * 16 + rr;
        const int kc = cc * 4;
        ushort4 o;
        o.x = f2bf(t[kc + 0][n]); o.y = f2bf(t[kc + 1][n]);
        o.z = f2bf(t[kc + 2][n]); o.w = f2bf(t[kc + 3][n]);
        *(ushort4*)(WT + (size_t)(n0 + n) * 1024 + k0 + kc) = o;
    }
}

// ---- bf16 MFMA GEMM: BK=64, global_load_lds + XOR chunk-swizzle ------------
template<typename CT>
__device__ __forceinline__ void gemm_tile_mfma(const ushort* __restrict__ A,
                                               const ushort* __restrict__ BT,
                                               CT* __restrict__ C,
                                               int brow, int bcol)
{
    __shared__ ushort As[128 * 64];
    __shared__ ushort Bs[128 * 64];
    const int tid  = threadIdx.x;
    const int lane = tid & 63;
    const int wv   = tid >> 6;
    const int wm   = (wv >> 1) * 64;
    const int wn   = (wv & 1) * 64;
    const int l15  = lane & 15;
    const int lq   = lane >> 4;

    f32x4 acc[4][4];
#pragma unroll
    for (int i = 0; i < 4; ++i)
#pragma unroll
        for (int j = 0; j < 4; ++j)
#pragma unroll
            for (int e = 0; e < 4; ++e) acc[i][j][e] = 0.f;

    for (int k0 = 0; k0 < 1024; k0 += 64) {
        __syncthreads();
#pragma unroll
        for (int j = 0; j < 4; ++j) {
            const int idx  = j * 256 + tid;
            const int row  = idx >> 3;
            const int gcol = ((idx & 7) ^ (row & 7)) * 8;   // inverse swizzle
            const int ldst = (j * 256 + wv * 64) * 8;       // wave-uniform
            gload16(A  + (size_t)(brow + row) * 1024 + k0 + gcol, As + ldst);
            gload16(BT + (size_t)(bcol + row) * 1024 + k0 + gcol, Bs + ldst);
        }
        __syncthreads();
#pragma unroll
        for (int kk = 0; kk < 2; ++kk) {
            short8 af[4], bf[4];
#pragma unroll
            for (int i = 0; i < 4; ++i) {
                const int ra = wm + i * 16 + l15;
                af[i] = *(const short8*)(As + ra * 64 + (((kk * 4 + lq) ^ (ra & 7)) * 8));
            }
#pragma unroll
            for (int j = 0; j < 4; ++j) {
                const int rb = wn + j * 16 + l15;
                bf[j] = *(const short8*)(Bs + rb * 64 + (((kk * 4 + lq) ^ (rb & 7)) * 8));
            }
#pragma unroll
            for (int i = 0; i < 4; ++i)
#pragma unroll
                for (int j = 0; j < 4; ++j)
                    acc[i][j] = MFMA(af[i], bf[j], acc[i][j], 0, 0, 0);
        }
    }
    const int l4 = lane >> 4;
#pragma unroll
    for (int i = 0; i < 4; ++i)
#pragma unroll
        for (int j = 0; j < 4; ++j)
#pragma unroll
            for (int r = 0; r < 4; ++r) {
                const size_t o = (size_t)(brow + wm + i * 16 + l4 * 4 + r) * 1024 +
                                 bcol + wn + j * 16 + l15;
                if constexpr (sizeof(CT) == 2) C[o] = f2bf(acc[i][j][r]);
                else                           C[o] = acc[i][j][r];
            }
}

__global__ __launch_bounds__(256)
void k_gemm4(const ushort* __restrict__ A, const ushort* __restrict__ WT,
             ushort* __restrict__ Cbase)
{
    const ushort* BT = WT + (size_t)blockIdx.z * (1024 * 1024);
    ushort* C = Cbase + (size_t)blockIdx.z * SZf;
    gemm_tile_mfma<ushort>(A, BT, C, blockIdx.y * 128, blockIdx.x * 128);
}

__global__ __launch_bounds__(256)
void k_gemm1(const ushort* __restrict__ A, const ushort* __restrict__ BT,
             float* __restrict__ C)
{
    gemm_tile_mfma<float>(A, BT, C, blockIdx.y * 128, blockIdx.x * 128);
}

// -------- alpha/beta small GEMM + sigmoid; writes TRANSPOSED [bh][t] --------
__global__ __launch_bounds__(256)
void k_ab(const float* __restrict__ x, const float* __restrict__ Wa,
          const float* __restrict__ ba, const float* __restrict__ Wb,
          const float* __restrict__ bb, float* __restrict__ aT,
          float* __restrict__ bT)
{
    const int r = blockIdx.x * 4 + (threadIdx.x >> 6);   // r = b*1024 + t
    const int lane = threadIdx.x & 63;
    const int b = r >> 10, t = r & 1023;
    const float* xr = x + (size_t)r * HID_;
    float acc[16];
#pragma unroll
    for (int n = 0; n < 16; ++n) acc[n] = 0.f;
    for (int c = lane; c < HID_; c += 64) {
        const float xv = xr[c];
        const float* wa = Wa + c * 8;
        const float* wb = Wb + c * 8;
#pragma unroll
        for (int n = 0; n < 8; ++n) {
            acc[n]     = fmaf(xv, wa[n], acc[n]);
            acc[8 + n] = fmaf(xv, wb[n], acc[8 + n]);
        }
    }
#pragma unroll
    for (int n = 0; n < 16; ++n) {
#pragma unroll
        for (int m = 32; m; m >>= 1) acc[n] += __shfl_xor(acc[n], m);
    }
    if (lane < 8) {
        aT[(size_t)(b * 8 + lane) * TSEQ + t] = sig_(acc[lane] + ba[lane]);
        bT[(size_t)(b * 8 + lane) * TSEQ + t] = sig_(acc[8 + lane] + bb[lane]);
    }
}

// ===== k_convprep: fused conv(K=4)+SiLU + stage + M/G/decays =================
// Phase A: waves 0-2 conv q/k/v into LDS; wave 3 cumsum + pug/pog/dtg/cv_s.
// Phase B: grams (all waves) -> Ef (f32 LDS) + Gc (global).
// Phase C: wave 0 register-unrolled M-solve -> Mc; waves 1-3 global dumps.
__global__ __launch_bounds__(256)
void k_convprep(const ushort* __restrict__ qb_, const ushort* __restrict__ kb_,
                const ushort* __restrict__ vb_,
                const float* __restrict__ wq, const float* __restrict__ bq,
                const float* __restrict__ wk, const float* __restrict__ bk,
                const float* __restrict__ wv, const float* __restrict__ bv,
                const float* __restrict__ aT, const float* __restrict__ bT,
                ushort* __restrict__ Kst, ushort* __restrict__ Qst,
                ushort* __restrict__ VstT, ushort* __restrict__ KTst,
                ushort* __restrict__ Mg, ushort* __restrict__ Gg,
                float* __restrict__ pug, float* __restrict__ pog,
                float* __restrict__ dtotg)
{
    const int cid = blockIdx.x;          // bh*16 + j
    const int bh = cid >> 4, j = cid & 15;
    const int b = bh >> 3, h = bh & 7;
    const int tid = threadIdx.x;
    const int t0 = j * LCH;

    __shared__ ushort Kb[64 * KSTR], Qb[64 * KSTR];
    __shared__ ushort Vl[128 * 72];
    __shared__ float Ef[64 * ESTR];
    __shared__ float cums[64], bv2[64], cv_s[64];

    if (tid >= 192) {                    // wave 3: cumsum + decay products
        const int lane = tid - 192;
        const float a = aT[(size_t)bh * TSEQ + t0 + lane];
        bv2[lane] = bT[(size_t)bh * TSEQ + t0 + lane];
        float cs = __logf(a);
#pragma unroll
        for (int d = 1; d < 64; d <<= 1) {
            float pv = __shfl_up(cs, d);
            if (lane >= d) cs += pv;
        }
        cums[lane] = cs;
        const float cp = __shfl_up(cs, 1);
        const float ctop = __shfl(cs, 63);
        pug[cid * 64 + lane] = (lane > 0) ? __expf(cp) : 1.f;
        pog[cid * 64 + lane] = __expf(cs);
        cv_s[lane] = __expf(ctop - cs);
        if (lane == 0) dtotg[cid] = __expf(ctop);
    } else {                             // waves 0-2: conv for q/k/v
        const int z = tid >> 6;          // 0=q 1=k 2=v
        const int c2 = (tid & 63) * 2;   // local channel pair (dk or dv)
        const ushort* src  = (z == 0) ? qb_ : (z == 1) ? kb_ : vb_;
        const float* w     = (z == 0) ? wq : (z == 1) ? wk : wv;
        const float* bias  = (z == 0) ? bq : (z == 1) ? bk : bv;
        const float scale  = (z == 1) ? 0.08838834764831845f : 1.f;
        const int gc = h * 128 + c2;     // global channel
        const float w0a = w[gc * 4],     w1a = w[gc * 4 + 1], w2a = w[gc * 4 + 2], w3a = w[gc * 4 + 3];
        const float w0b = w[gc * 4 + 4], w1b = w[gc * 4 + 5], w2b = w[gc * 4 + 6], w3b = w[gc * 4 + 7];
        const float bsa = bias[gc], bsb = bias[gc + 1];
        float ya0 = 0.f, ya1 = 0.f, ya2 = 0.f, yb0 = 0.f, yb1 = 0.f, yb2 = 0.f;
        if (j > 0) {
#pragma unroll
            for (int i = 0; i < 3; ++i) {
                uint u = *(const uint*)(src + (size_t)(b * TSEQ + t0 - 3 + i) * HID_ + gc);
                const float lo = bf2f((ushort)u), hi = bf2f((ushort)(u >> 16));
                if (i == 0) { ya0 = lo; yb0 = hi; }
                else if (i == 1) { ya1 = lo; yb1 = hi; }
                else { ya2 = lo; yb2 = hi; }
            }
        }
#pragma unroll 4
        for (int tl = 0; tl < 64; ++tl) {
            uint u = *(const uint*)(src + (size_t)(b * TSEQ + t0 + tl) * HID_ + gc);
            const float x0 = bf2f((ushort)u), x1 = bf2f((ushort)(u >> 16));
            float a0 = fmaf(w0a, ya0, fmaf(w1a, ya1, fmaf(w2a, ya2, fmaf(w3a, x0, bsa))));
            float a1 = fmaf(w0b, yb0, fmaf(w1b, yb1, fmaf(w2b, yb2, fmaf(w3b, x1, bsb))));
            const float s0 = a0 * sig_(a0) * scale;
            const float s1 = a1 * sig_(a1) * scale;
            if (z == 0)      *(uint*)(Qb + tl * KSTR + c2) = pk2(s0, s1);
            else if (z == 1) *(uint*)(Kb + tl * KSTR + c2) = pk2(s0, s1);
            else {
                Vl[(c2 + 0) * 72 + tl] = f2bf(s0);
                Vl[(c2 + 1) * 72 + tl] = f2bf(s1);
            }
            ya0 = ya1; ya1 = ya2; ya2 = x0;
            yb0 = yb1; yb1 = yb2; yb2 = x1;
        }
    }
    __syncthreads();

    // ---- Phase B: grams -> Ef (LDS) + Gc (global)
    const int wv2 = tid >> 6, l = tid & 63, l15 = l & 15, lq = l >> 4;
    const int k8o = lq * 8;
    f32x4 accK[4], accQ4[4];
#pragma unroll
    for (int jx = 0; jx < 4; ++jx) {
        accK[jx] = f32x4{0.f, 0.f, 0.f, 0.f};
        accQ4[jx] = f32x4{0.f, 0.f, 0.f, 0.f};
    }
#pragma unroll
    for (int kk = 0; kk < 4; ++kk) {
        short8 aK = *(const short8*)(Kb + (wv2 * 16 + l15) * KSTR + kk * 32 + k8o);
        short8 aQ = *(const short8*)(Qb + (wv2 * 16 + l15) * KSTR + kk * 32 + k8o);
#pragma unroll
        for (int js = 0; js < 4; ++js) {
            short8 bK = *(const short8*)(Kb + (js * 16 + l15) * KSTR + kk * 32 + k8o);
            accK[js]  = MFMA(aK, bK, accK[js], 0, 0, 0);
            accQ4[js] = MFMA(aQ, bK, accQ4[js], 0, 0, 0);
        }
    }
    ushort* Gc = Gg + (size_t)cid * 4096;
#pragma unroll
    for (int js = 0; js < 4; ++js) {
#pragma unroll
        for (int r = 0; r < 4; ++r) {
            const int t = wv2 * 16 + lq * 4 + r;
            const int s = js * 16 + l15;
            const float cp = (t > 0) ? cums[t - 1] : 0.f;
            Ef[t * ESTR + s] = (s < t) ? __expf(cp - cums[s]) * accK[js][r] : 0.f;
            const float gv = (s <= t) ? __expf(cums[t] - cums[s]) * accQ4[js][r] : 0.f;
            Gc[t * 64 + s] = f2bf(gv);
        }
    }
    __syncthreads();

    // ---- Phase C: wave 0 M-solve (registers, fully static); waves 1-3 dumps
    const size_t go = (size_t)cid * 8192;
    if (wv2 == 0) {
        const int s = l;                 // lane = column
        ushort* Mc = Mg + (size_t)cid * 4096;
        float Mreg[64];
        const float bvs = bv2[s];
#pragma unroll
        for (int r = 0; r < 64; ++r) Mreg[r] = (r == s) ? bvs : 0.f;
#pragma unroll
        for (int t = 1; t < 64; ++t) {
            float a0 = 0.f, a1 = 0.f, a2 = 0.f, a3 = 0.f;
#pragma unroll
            for (int r4 = 0; r4 < 64; r4 += 4) {
                if (r4 < t) {
                    float4 e = *(const float4*)(Ef + t * ESTR + r4);
                    if (r4 + 0 < t) a0 = fmaf(e.x, Mreg[r4 + 0], a0);
                    if (r4 + 1 < t) a1 = fmaf(e.y, Mreg[r4 + 1], a1);
                    if (r4 + 2 < t) a2 = fmaf(e.z, Mreg[r4 + 2], a2);
                    if (r4 + 3 < t) a3 = fmaf(e.w, Mreg[r4 + 3], a3);
                }
            }
            const float mt = -bv2[t] * ((a0 + a1) + (a2 + a3));
            Mreg[t] = (s < t) ? mt : Mreg[t];
        }
#pragma unroll
        for (int r = 0; r < 64; ++r)      // row r: 64 lanes = 128B coalesced
            Mc[r * 64 + s] = f2bf(Mreg[r]);
    } else {
        const int st = tid - 64;          // 0..191
        for (int i = st; i < 1024; i += 192) {
            const int row = i >> 4, col = (i & 15) * 8;
            *(uint4*)(Kst + go + i * 8) = *(const uint4*)(Kb + row * KSTR + col);
            *(uint4*)(Qst + go + i * 8) = *(const uint4*)(Qb + row * KSTR + col);
        }
        for (int i = st; i < 1024; i += 192) {
            const int dv = i >> 3, tq = (i & 7) * 8;
            *(uint4*)(VstT + go + dv * 64 + tq) = *(const uint4*)(Vl + dv * 72 + tq);
            const int dk = i >> 3, tt = (i & 7) * 8;
            ushort tmp[8];
#pragma unroll
            for (int e = 0; e < 8; ++e)
                tmp[e] = f2bf(bf2f(Kb[(tt + e) * KSTR + dk]) * cv_s[tt + e]);
            *(uint4*)(KTst + go + dk * 64 + tt) = *(uint4*)tmp;
        }
    }
}

// ===== kernel S (serial): swapped-operand chain; single-buffer staging, =====
// 2 barriers/chunk (verified 60us structure from R14; dbuf variant regressed).
__global__ __launch_bounds__(256)
void k_scan2(const ushort* __restrict__ Kst, const ushort* __restrict__ KTst,
             const ushort* __restrict__ VstT, const ushort* __restrict__ Mg,
             const float* __restrict__ pug, const float* __restrict__ dtg,
             ushort* __restrict__ Sst, ushort* __restrict__ Wst)
{
    const int blk = blockIdx.x;          // bh*2 + half
    const int bh = blk >> 1, half = blk & 1;
    const int tid = threadIdx.x;
    const int wv = tid >> 6, l = tid & 63, l15 = l & 15, lq = l >> 4;
    const int k8o = lq * 8;
    const int dvw = wv * 16;

    __shared__ ushort Kb[64 * KSTR];
    __shared__ ushort KTb[128 * 72];
    __shared__ ushort Mb[64 * 72];
    __shared__ ushort Vb[64 * 72];
    __shared__ ushort Shb[64 * KSTR], Slb[64 * KSTR];
    __shared__ ushort Yb[64 * 72], Wb[64 * 72];
    __shared__ float puv[64], dts[1];

    f32x4 accS[8];
#pragma unroll
    for (int m = 0; m < 8; ++m) accS[m] = f32x4{0.f, 0.f, 0.f, 0.f};

    uint4 rk[4], rkt[4], rm[2], rv[2];
    float rpu = 0.f, rdt = 0.f;

    auto LOADC = [&](int cc) {
        const int cid = bh * 16 + cc;
        const size_t go = (size_t)cid * 8192;
#pragma unroll
        for (int jx = 0; jx < 4; ++jx) {
            rk[jx]  = *(const uint4*)(Kst  + go + (tid + jx * 256) * 8);
            rkt[jx] = *(const uint4*)(KTst + go + (tid + jx * 256) * 8);
        }
#pragma unroll
        for (int jx = 0; jx < 2; ++jx) {
            rm[jx] = *(const uint4*)(Mg + (size_t)cid * 4096 + (tid + jx * 256) * 8);
            rv[jx] = *(const uint4*)(VstT + go + half * 4096 + (tid + jx * 256) * 8);
        }
        if (tid < 64) {
            rpu = pug[cid * 64 + tid];
            if (tid == 0) rdt = dtg[cid];
        }
    };
    auto WRITEC = [&]() {
#pragma unroll
        for (int jx = 0; jx < 4; ++jx) {
            const int i16 = tid + jx * 256;
            *(uint4*)(Kb  + (i16 >> 4) * KSTR + (i16 & 15) * 8) = rk[jx];
            *(uint4*)(KTb + (i16 >> 3) * 72   + (i16 & 7) * 8)  = rkt[jx];
        }
#pragma unroll
        for (int jx = 0; jx < 2; ++jx) {
            const int i8 = tid + jx * 256;
            *(uint4*)(Mb + (i8 >> 3) * 72 + (i8 & 7) * 8) = rm[jx];
            *(uint4*)(Vb + (i8 >> 3) * 72 + (i8 & 7) * 8) = rv[jx];
        }
        if (tid < 64) {
            puv[tid] = rpu;
            if (tid == 0) dts[0] = rdt;
        }
    };

    LOADC(0); WRITEC();
    __syncthreads();

    for (int c = 0; c < NCK; ++c) {
        if (c + 1 < NCK) LOADC(c + 1);       // in flight through compute

        // ---- B: state (S^T acc) -> Shb/Slb [dv][dk] via b64 writes
#pragma unroll
        for (int m = 0; m < 8; ++m) {
            ushort h4[4], l4v[4];
#pragma unroll
            for (int r = 0; r < 4; ++r) {
                const float sv = accS[m][r];
                const ushort hi = f2bf(sv);
                h4[r] = hi;
                l4v[r] = f2bf(sv - bf2f(hi));
            }
            *(uint2*)(Shb + (dvw + l15) * KSTR + m * 16 + lq * 4) = *(uint2*)h4;
            *(uint2*)(Slb + (dvw + l15) * KSTR + m * 16 + lq * 4) = *(uint2*)l4v;
        }
        // ---- C': U^T = K.S^T (compensated)
        f32x4 accU[4];
#pragma unroll
        for (int jj = 0; jj < 4; ++jj) accU[jj] = f32x4{0.f, 0.f, 0.f, 0.f};
#pragma unroll
        for (int kk = 0; kk < 4; ++kk) {
            short8 sh = *(const short8*)(Shb + (dvw + l15) * KSTR + kk * 32 + k8o);
            short8 sl = *(const short8*)(Slb + (dvw + l15) * KSTR + kk * 32 + k8o);
#pragma unroll
            for (int jj = 0; jj < 4; ++jj) {
                short8 ka = *(const short8*)(Kb + (jj * 16 + l15) * KSTR + kk * 32 + k8o);
                accU[jj] = MFMA(ka, sh, accU[jj], 0, 0, 0);
                accU[jj] = MFMA(ka, sl, accU[jj], 0, 0, 0);
            }
        }
        // ---- D': Y[dv][t] = V - pu (.) U (lane-local b64)
#pragma unroll
        for (int jj = 0; jj < 4; ++jj) {
            float pu4[4];
            *(float4*)pu4 = *(const float4*)(puv + jj * 16 + lq * 4);
            ushort v4[4];
            *(uint2*)v4 = *(const uint2*)(Vb + (dvw + l15) * 72 + jj * 16 + lq * 4);
            ushort y4[4];
#pragma unroll
            for (int r = 0; r < 4; ++r)
                y4[r] = f2bf(bf2f(v4[r]) - pu4[r] * accU[jj][r]);
            *(uint2*)(Yb + (dvw + l15) * 72 + jj * 16 + lq * 4) = *(uint2*)y4;
        }
        // ---- E'': W^T = M.Y
        f32x4 accW[4];
#pragma unroll
        for (int jj = 0; jj < 4; ++jj) accW[jj] = f32x4{0.f, 0.f, 0.f, 0.f};
#pragma unroll
        for (int kk = 0; kk < 2; ++kk) {
            short8 yb = *(const short8*)(Yb + (dvw + l15) * 72 + kk * 32 + k8o);
#pragma unroll
            for (int jj = 0; jj < 4; ++jj) {
                short8 mf = *(const short8*)(Mb + (jj * 16 + l15) * 72 + kk * 32 + k8o);
                accW[jj] = MFMA(mf, yb, accW[jj], 0, 0, 0);
            }
        }
#pragma unroll
        for (int jj = 0; jj < 4; ++jj) {
            ushort w4[4];
#pragma unroll
            for (int r = 0; r < 4; ++r)
                w4[r] = f2bf(accW[jj][r]);
            *(uint2*)(Wb + (dvw + l15) * 72 + jj * 16 + lq * 4) = *(uint2*)w4;
        }
        // ---- G: S^T = dtot.S^T + KTc.W   (KT pre-scaled by cv)
        const float dt = dts[0];
#pragma unroll
        for (int m = 0; m < 8; ++m)
#pragma unroll
            for (int r = 0; r < 4; ++r) accS[m][r] *= dt;
#pragma unroll
        for (int kk = 0; kk < 2; ++kk) {
            short8 wc = *(const short8*)(Wb + (dvw + l15) * 72 + kk * 32 + k8o);
#pragma unroll
            for (int m = 0; m < 8; ++m) {
                short8 kt = *(const short8*)(KTb + (m * 16 + l15) * 72 + kk * 32 + k8o);
                accS[m] = MFMA(kt, wc, accS[m], 0, 0, 0);
            }
        }
        // ---- dumps (wave-local rows of Shb/Wb)
        {
            const int cid = bh * 16 + c;
#pragma unroll
            for (int jx = 0; jx < 4; ++jx) {
                const int idx = l + jx * 64;
                const int dvo = idx >> 4, ko = (idx & 15) * 8;
                *(uint4*)(Sst + (size_t)cid * 16384 +
                          (half * 64 + dvw + dvo) * 128 + ko) =
                    *(const uint4*)(Shb + (dvw + dvo) * KSTR + ko);
            }
#pragma unroll
            for (int jx = 0; jx < 2; ++jx) {
                const int idx = l + jx * 64;
                const int dvo = idx >> 3, t8 = (idx & 7) * 8;
                *(uint4*)(Wst + (size_t)cid * 8192 +
                          (half * 64 + dvw + dvo) * 64 + t8) =
                    *(const uint4*)(Wb + (dvw + dvo) * 72 + t8);
            }
        }
        __syncthreads();        // all reads of shared bufs done
        if (c + 1 < NCK) WRITEC();
        __syncthreads();        // staged chunk visible
    }
}

// ===== kernel O (parallel): O = po (.) S.Q^T + G.W, fused LayerNorm + gate ====
__global__ __launch_bounds__(256)
void k_out(const ushort* __restrict__ Sst, const ushort* __restrict__ Qst,
           const ushort* __restrict__ Gg, const ushort* __restrict__ Wst,
           const float* __restrict__ pog, const ushort* __restrict__ gb_,
           const float* __restrict__ lng, const float* __restrict__ lnb,
           ushort* __restrict__ ogb)
{
    const int cid = blockIdx.x;
    const int bh = cid >> 4, c = cid & 15;
    const int b = bh >> 3, h = bh & 7;
    const int t0 = c * LCH;
    const int tid = threadIdx.x;
    const int wv = tid >> 6, l = tid & 63, l15 = l & 15, lq = l >> 4;
    const int k8o = lq * 8;

    __shared__ ushort Sb[128 * KSTR];
    __shared__ ushort Qb[64 * KSTR];
    __shared__ ushort Gb[64 * 72];
    __shared__ ushort Wqb[128 * 72];
    __shared__ float  Ot[64 * 132];
    __shared__ float  pov[64];

#pragma unroll
    for (int jx = 0; jx < 8; ++jx) {
        const int i16 = tid + jx * 256;
        *(uint4*)(Sb + (i16 >> 4) * KSTR + (i16 & 15) * 8) =
            *(const uint4*)(Sst + (size_t)cid * 16384 + i16 * 8);
    }
#pragma unroll
    for (int jx = 0; jx < 4; ++jx) {
        const int i16 = tid + jx * 256;
        *(uint4*)(Qb + (i16 >> 4) * KSTR + (i16 & 15) * 8) =
            *(const uint4*)(Qst + (size_t)cid * 8192 + i16 * 8);
        *(uint4*)(Wqb + (i16 >> 3) * 72 + (i16 & 7) * 8) =
            *(const uint4*)(Wst + (size_t)cid * 8192 + i16 * 8);
    }
#pragma unroll
    for (int jx = 0; jx < 2; ++jx) {
        const int i8 = tid + jx * 256;
        *(uint4*)(Gb + (i8 >> 3) * 72 + (i8 & 7) * 8) =
            *(const uint4*)(Gg + (size_t)cid * 4096 + i8 * 8);
    }
    if (tid < 64) pov[tid] = pog[cid * 64 + tid];
    __syncthreads();

#pragma unroll
    for (int i = 0; i < 2; ++i) {
        const int dvt = wv * 2 + i;
        f32x4 acc[4], acg[4];
#pragma unroll
        for (int jj = 0; jj < 4; ++jj) {
            acc[jj] = f32x4{0.f, 0.f, 0.f, 0.f};
            acg[jj] = f32x4{0.f, 0.f, 0.f, 0.f};
        }
#pragma unroll
        for (int kk = 0; kk < 4; ++kk) {
            short8 sa = *(const short8*)(Sb + (dvt * 16 + l15) * KSTR + kk * 32 + k8o);
#pragma unroll
            for (int jj = 0; jj < 4; ++jj) {
                short8 qb = *(const short8*)(Qb + (jj * 16 + l15) * KSTR + kk * 32 + k8o);
                acc[jj] = MFMA(sa, qb, acc[jj], 0, 0, 0);
            }
        }
#pragma unroll
        for (int kk = 0; kk < 2; ++kk) {
            short8 wa = *(const short8*)(Wqb + (dvt * 16 + l15) * 72 + kk * 32 + k8o);
#pragma unroll
            for (int jj = 0; jj < 4; ++jj) {
                short8 gb = *(const short8*)(Gb + (jj * 16 + l15) * 72 + kk * 32 + k8o);
                acg[jj] = MFMA(wa, gb, acg[jj], 0, 0, 0);
            }
        }
#pragma unroll
        for (int jj = 0; jj < 4; ++jj) {
            const int t = jj * 16 + l15;
            const float po = pov[t];
            float4 o4;
            o4.x = po * acc[jj][0] + acg[jj][0];
            o4.y = po * acc[jj][1] + acg[jj][1];
            o4.z = po * acc[jj][2] + acg[jj][2];
            o4.w = po * acc[jj][3] + acg[jj][3];
            *(float4*)(Ot + t * 132 + dvt * 16 + lq * 4) = o4;
        }
    }
    __syncthreads();

    const int d = l * 2;
    const float lg0 = lng[d], lg1 = lng[d + 1];
    const float lb0 = lnb[d], lb1 = lnb[d + 1];
    const size_t btbase = (size_t)b * TSEQ + t0 + wv * 16;
#pragma unroll 1
    for (int rr = 0; rr < 16; ++rr) {
        const int t = wv * 16 + rr;
        float2 xv = *(const float2*)(Ot + t * 132 + d);
        float s = xv.x + xv.y;
#pragma unroll
        for (int m = 32; m; m >>= 1) s += __shfl_xor(s, m);
        const float mu = s * (1.f / 128.f);
        const float d0 = xv.x - mu, d1 = xv.y - mu;
        float v = d0 * d0 + d1 * d1;
#pragma unroll
        for (int m = 32; m; m >>= 1) v += __shfl_xor(v, m);
        const float inv = rsqrtf(v * (1.f / 128.f) + 1e-5f);
        const uint gu = *(const uint*)(gb_ + (btbase + rr) * HID_ + h * DV + d);
        const float g0 = sig_(bf2f((ushort)gu)), g1 = sig_(bf2f((ushort)(gu >> 16)));
        const float y0 = (d0 * inv * lg0 + lb0) * g0;
        const float y1 = (d1 * inv * lg1 + lb1) * g1;
        *(uint*)(ogb + (btbase + rr) * HID_ + h * DV + d) = pk2(y0, y1);
    }
}

extern "C" void kernel_launch(void* const* d_in, const int* in_sizes, int n_in,
                              void* d_out, int out_size, void* d_ws, size_t ws_size,
                              hipStream_t stream)
{
    const float* x   = (const float*)d_in[0];
    const float* Wq  = (const float*)d_in[1];
    const float* Wk  = (const float*)d_in[2];
    const float* Wv  = (const float*)d_in[3];
    const float* cqw = (const float*)d_in[4];
    const float* cqb = (const float*)d_in[5];
    const float* ckw = (const float*)d_in[6];
    const float* ckb = (const float*)d_in[7];
    const float* cvw = (const float*)d_in[8];
    const float* cvb = (const float*)d_in[9];
    const float* Wa  = (const float*)d_in[10];
    const float* ba  = (const float*)d_in[11];
    const float* Wb  = (const float*)d_in[12];
    const float* bb  = (const float*)d_in[13];
    const float* Wg  = (const float*)d_in[14];
    const float* Wo  = (const float*)d_in[15];
    const float* lng = (const float*)d_in[16];
    const float* lnb = (const float*)d_in[17];
    float* out = (float*)d_out;
    float* ws  = (float*)d_ws;

    ushort* qb_ = (ushort*)ws;
    ushort* kb_ = qb_ + (size_t)SZf;
    ushort* vb_ = qb_ + (size_t)2 * SZf;
    ushort* gb_ = qb_ + (size_t)3 * SZf;

    ushort* ogb  = (ushort*)(ws + 2 * (size_t)SZf);           // 4MB (lo)
    ushort* VstT = ogb + (size_t)2 * 1024 * 1024;             // 4MB (hi)
    ushort* WoT  = (ushort*)(ws + 3 * (size_t)SZf);           // 2MB (free region)
    float*  o_buf = ws + 4 * (size_t)SZf;
    ushort* WT4  = (ushort*)o_buf;                            // 8MB, dead after gemm4
    ushort* Sst  = (ushort*)o_buf;                            // 8MB (scan out)
    float* aT  = ws + 5 * (size_t)SZf;
    float* bT  = aT + 16 * TSEQ;
    float* pug = bT + 16 * TSEQ;
    float* pog = pug + 256 * 64;
    float* dtg = pog + 256 * 64;

    float*  tail = ws + 5 * (size_t)SZf + 131072;
    ushort* Kst  = (ushort*)tail;                             // 4MB
    ushort* Qst  = Kst + (size_t)256 * 8192;                  // 4MB
    ushort* xbf  = Qst + (size_t)256 * 8192;                  // 4MB; dead after gemm4
    ushort* KTst = xbf;                                       // reuse

    ushort* Mg  = (ushort*)out;                               // 2MB
    ushort* Gg  = Mg + (size_t)256 * 4096;                    // 2MB
    ushort* Wst = Gg + (size_t)256 * 4096;                    // 4MB

    k_x2bf<<<1024, 256, 0, stream>>>(x, xbf);
    k_wT<<<dim3(16, 16, 5), 256, 0, stream>>>(Wq, Wk, Wv, Wg, Wo, WT4, WoT);
    k_gemm4<<<dim3(8, 16, 4), 256, 0, stream>>>(xbf, WT4, qb_);
    k_ab<<<512, 256, 0, stream>>>(x, Wa, ba, Wb, bb, aT, bT);
    k_convprep<<<256, 256, 0, stream>>>(qb_, kb_, vb_,
                                        cqw, cqb, ckw, ckb, cvw, cvb,
                                        aT, bT, Kst, Qst, VstT, KTst,
                                        Mg, Gg, pug, pog, dtg);
    k_scan2<<<32, 256, 0, stream>>>(Kst, KTst, VstT, Mg, pug, dtg, Sst, Wst);
    k_out<<<256, 256, 0, stream>>>(Sst, Qst, Gg, Wst, pog, gb_, lng, lnb, ogb);
    k_gemm1<<<dim3(8, 16), 256, 0, stream>>>(ogb, WoT, out);
}

// Round 22
// 207.088 us; speedup vs baseline: 1.1243x; 1.1243x over previous
//
#include <hip/hip_runtime.h>

#define TSEQ 1024
#define HID_ 1024
#define NH 8
#define DK 128
#define DV 128
#define ROWS 2048               // B*T
#define SZf (ROWS * HID_)       // elements per [2048,1024] matrix
#define LCH 64                  // scan chunk length
#define NCK 16                  // chunks per (b,h)
#define KSTR 136                // bf16 LDS stride
#define ESTR 68                 // f32 LDS stride (16B-aligned rows)

typedef __attribute__((ext_vector_type(8))) short short8;
typedef __attribute__((ext_vector_type(4))) float f32x4;
#define MFMA __builtin_amdgcn_mfma_f32_16x16x32_bf16

__device__ __forceinline__ float sig_(float x) { return 1.f / (1.f + __expf(-x)); }

__device__ __forceinline__ ushort f2bf(float f) {   // RNE f32->bf16
    unsigned int u = __builtin_bit_cast(unsigned int, f);
    u += 0x7FFF + ((u >> 16) & 1);
    return (ushort)(u >> 16);
}
__device__ __forceinline__ float bf2f(ushort u) {
    return __builtin_bit_cast(float, ((unsigned int)u) << 16);
}
__device__ __forceinline__ unsigned int pk2(float lo, float hi) {
    return (unsigned int)f2bf(lo) | ((unsigned int)f2bf(hi) << 16);
}

// async global->LDS, 16B per lane; dst = wave-uniform base (+lane*16 by HW)
__device__ __forceinline__ void gload16(const void* g, void* l) {
    __builtin_amdgcn_global_load_lds(
        (const __attribute__((address_space(1))) unsigned int*)g,
        (__attribute__((address_space(3))) unsigned int*)l, 16, 0, 0);
}

// ---------------- x -> bf16 ----------------
__global__ __launch_bounds__(256)
void k_x2bf(const float* __restrict__ x, ushort* __restrict__ xb)
{
    const size_t i8 = (size_t)blockIdx.x * 256 + threadIdx.x;   // grid 1024
    float4 v0 = *(const float4*)(x + i8 * 8);
    float4 v1 = *(const float4*)(x + i8 * 8 + 4);
    uint4 o;
    o.x = pk2(v0.x, v0.y); o.y = pk2(v0.z, v0.w);
    o.z = pk2(v1.x, v1.y); o.w = pk2(v1.z, v1.w);
    *(uint4*)(xb + i8 * 8) = o;
}

// -------- weight transpose+convert: W f32 [K][N] -> WT bf16 [N][K]; z=4 -> Wo
__global__ __launch_bounds__(256)
void k_wT(const float* __restrict__ s0, const float* __restrict__ s1,
          const float* __restrict__ s2, const float* __restrict__ s3,
          const float* __restrict__ s4,
          ushort* __restrict__ dst, ushort* __restrict__ dstWo)
{
    const int z = blockIdx.z;
    const float* W = (z == 0) ? s0 : (z == 1) ? s1 : (z == 2) ? s2
                   : (z == 3) ? s3 : s4;
    ushort* WT = (z < 4) ? dst + (size_t)z * (1024 * 1024) : dstWo;
    __shared__ float t[64][65];
    const int n0 = blockIdx.x * 64, k0 = blockIdx.y * 64;
    const int rr = threadIdx.x >> 4, cc = threadIdx.x & 15;
#pragma unroll
    for (int i = 0; i < 4; ++i) {
        const int row = i * 16 + rr;
        float4 v = *(const float4*)(W + (size_t)(k0 + row) * 1024 + n0 + cc * 4);
        t[row][cc * 4 + 0] = v.x; t[row][cc * 4 + 1] = v.y;
        t[row][cc * 4 + 2] = v.z; t[row][cc * 4 + 3] = v.w;
    }
    __syncthreads();
#pragma unroll
    for (int i = 0; i < 4; ++i) {
        const int n = i * 16 + rr;
        const int kc = cc * 4;
        ushort4 o;
        o.x = f2bf(t[kc + 0][n]); o.y = f2bf(t[kc + 1][n]);
        o.z = f2bf(t[kc + 2][n]); o.w = f2bf(t[kc + 3][n]);
        *(ushort4*)(WT + (size_t)(n0 + n) * 1024 + k0 + kc) = o;
    }
}

// ---- bf16 MFMA GEMM: BK=64, global_load_lds + XOR chunk-swizzle ------------
template<typename CT>
__device__ __forceinline__ void gemm_tile_mfma(const ushort* __restrict__ A,
                                               const ushort* __restrict__ BT,
                                               CT* __restrict__ C,
                                               int brow, int bcol)
{
    __shared__ ushort As[128 * 64];
    __shared__ ushort Bs[128 * 64];
    const int tid  = threadIdx.x;
    const int lane = tid & 63;
    const int wv   = tid >> 6;
    const int wm   = (wv >> 1) * 64;
    const int wn   = (wv & 1) * 64;
    const int l15  = lane & 15;
    const int lq   = lane >> 4;

    f32x4 acc[4][4];
#pragma unroll
    for (int i = 0; i < 4; ++i)
#pragma unroll
        for (int j = 0; j < 4; ++j)
#pragma unroll
            for (int e = 0; e < 4; ++e) acc[i][j][e] = 0.f;

    for (int k0 = 0; k0 < 1024; k0 += 64) {
        __syncthreads();
#pragma unroll
        for (int j = 0; j < 4; ++j) {
            const int idx  = j * 256 + tid;
            const int row  = idx >> 3;
            const int gcol = ((idx & 7) ^ (row & 7)) * 8;   // inverse swizzle
            const int ldst = (j * 256 + wv * 64) * 8;       // wave-uniform
            gload16(A  + (size_t)(brow + row) * 1024 + k0 + gcol, As + ldst);
            gload16(BT + (size_t)(bcol + row) * 1024 + k0 + gcol, Bs + ldst);
        }
        __syncthreads();
#pragma unroll
        for (int kk = 0; kk < 2; ++kk) {
            short8 af[4], bf[4];
#pragma unroll
            for (int i = 0; i < 4; ++i) {
                const int ra = wm + i * 16 + l15;
                af[i] = *(const short8*)(As + ra * 64 + (((kk * 4 + lq) ^ (ra & 7)) * 8));
            }
#pragma unroll
            for (int j = 0; j < 4; ++j) {
                const int rb = wn + j * 16 + l15;
                bf[j] = *(const short8*)(Bs + rb * 64 + (((kk * 4 + lq) ^ (rb & 7)) * 8));
            }
#pragma unroll
            for (int i = 0; i < 4; ++i)
#pragma unroll
                for (int j = 0; j < 4; ++j)
                    acc[i][j] = MFMA(af[i], bf[j], acc[i][j], 0, 0, 0);
        }
    }
    const int l4 = lane >> 4;
#pragma unroll
    for (int i = 0; i < 4; ++i)
#pragma unroll
        for (int j = 0; j < 4; ++j)
#pragma unroll
            for (int r = 0; r < 4; ++r) {
                const size_t o = (size_t)(brow + wm + i * 16 + l4 * 4 + r) * 1024 +
                                 bcol + wn + j * 16 + l15;
                if constexpr (sizeof(CT) == 2) C[o] = f2bf(acc[i][j][r]);
                else                           C[o] = acc[i][j][r];
            }
}

__global__ __launch_bounds__(256)
void k_gemm4(const ushort* __restrict__ A, const ushort* __restrict__ WT,
             ushort* __restrict__ Cbase)
{
    const ushort* BT = WT + (size_t)blockIdx.z * (1024 * 1024);
    ushort* C = Cbase + (size_t)blockIdx.z * SZf;
    gemm_tile_mfma<ushort>(A, BT, C, blockIdx.y * 128, blockIdx.x * 128);
}

__global__ __launch_bounds__(256)
void k_gemm1(const ushort* __restrict__ A, const ushort* __restrict__ BT,
             float* __restrict__ C)
{
    gemm_tile_mfma<float>(A, BT, C, blockIdx.y * 128, blockIdx.x * 128);
}

// -------- alpha/beta small GEMM + sigmoid; writes TRANSPOSED [bh][t] --------
__global__ __launch_bounds__(256)
void k_ab(const float* __restrict__ x, const float* __restrict__ Wa,
          const float* __restrict__ ba, const float* __restrict__ Wb,
          const float* __restrict__ bb, float* __restrict__ aT,
          float* __restrict__ bT)
{
    const int r = blockIdx.x * 4 + (threadIdx.x >> 6);   // r = b*1024 + t
    const int lane = threadIdx.x & 63;
    const int b = r >> 10, t = r & 1023;
    const float* xr = x + (size_t)r * HID_;
    float acc[16];
#pragma unroll
    for (int n = 0; n < 16; ++n) acc[n] = 0.f;
    for (int c = lane; c < HID_; c += 64) {
        const float xv = xr[c];
        const float* wa = Wa + c * 8;
        const float* wb = Wb + c * 8;
#pragma unroll
        for (int n = 0; n < 8; ++n) {
            acc[n]     = fmaf(xv, wa[n], acc[n]);
            acc[8 + n] = fmaf(xv, wb[n], acc[8 + n]);
        }
    }
#pragma unroll
    for (int n = 0; n < 16; ++n) {
#pragma unroll
        for (int m = 32; m; m >>= 1) acc[n] += __shfl_xor(acc[n], m);
    }
    if (lane < 8) {
        aT[(size_t)(b * 8 + lane) * TSEQ + t] = sig_(acc[lane] + ba[lane]);
        bT[(size_t)(b * 8 + lane) * TSEQ + t] = sig_(acc[8 + lane] + bb[lane]);
    }
}

// ===== k_convprep: fused conv(K=4)+SiLU + stage + M/G/decays =================
// Phase A: waves 0-2 conv q/k/v into LDS; wave 3 cumsum + pug/pog/dtg/cv_s.
// Phase B: grams (all waves) -> Ef, Gl (LDS).
// Phase C: wave 0 LDS M-solve (+Mc dump); waves 1-3 coalesced global dumps.
__global__ __launch_bounds__(256)
void k_convprep(const ushort* __restrict__ qb_, const ushort* __restrict__ kb_,
                const ushort* __restrict__ vb_,
                const float* __restrict__ wq, const float* __restrict__ bq,
                const float* __restrict__ wk, const float* __restrict__ bk,
                const float* __restrict__ wv, const float* __restrict__ bv,
                const float* __restrict__ aT, const float* __restrict__ bT,
                ushort* __restrict__ Kst, ushort* __restrict__ Qst,
                ushort* __restrict__ VstT, ushort* __restrict__ KTst,
                ushort* __restrict__ Mg, ushort* __restrict__ Gg,
                float* __restrict__ pug, float* __restrict__ pog,
                float* __restrict__ dtotg)
{
    const int cid = blockIdx.x;          // bh*16 + j
    const int bh = cid >> 4, j = cid & 15;
    const int b = bh >> 3, h = bh & 7;
    const int tid = threadIdx.x;
    const int t0 = j * LCH;

    __shared__ ushort Kb[64 * KSTR], Qb[64 * KSTR];
    __shared__ ushort Vl[128 * 72];
    __shared__ ushort Gl[64 * 64];
    __shared__ float Ef[64 * ESTR];
    __shared__ float Mf[64 * ESTR];
    __shared__ float cums[64], bv2[64], cv_s[64];

    if (tid >= 192) {                    // wave 3: cumsum + decay products
        const int lane = tid - 192;
        const float a = aT[(size_t)bh * TSEQ + t0 + lane];
        bv2[lane] = bT[(size_t)bh * TSEQ + t0 + lane];
        float cs = __logf(a);
#pragma unroll
        for (int d = 1; d < 64; d <<= 1) {
            float pv = __shfl_up(cs, d);
            if (lane >= d) cs += pv;
        }
        cums[lane] = cs;
        const float cp = __shfl_up(cs, 1);
        const float ctop = __shfl(cs, 63);
        pug[cid * 64 + lane] = (lane > 0) ? __expf(cp) : 1.f;
        pog[cid * 64 + lane] = __expf(cs);
        cv_s[lane] = __expf(ctop - cs);
        if (lane == 0) dtotg[cid] = __expf(ctop);
    } else {                             // waves 0-2: conv for q/k/v
        const int z = tid >> 6;          // 0=q 1=k 2=v
        const int c2 = (tid & 63) * 2;   // local channel pair (dk or dv)
        const ushort* src  = (z == 0) ? qb_ : (z == 1) ? kb_ : vb_;
        const float* w     = (z == 0) ? wq : (z == 1) ? wk : wv;
        const float* bias  = (z == 0) ? bq : (z == 1) ? bk : bv;
        const float scale  = (z == 1) ? 0.08838834764831845f : 1.f;
        const int gc = h * 128 + c2;     // global channel
        const float w0a = w[gc * 4],     w1a = w[gc * 4 + 1], w2a = w[gc * 4 + 2], w3a = w[gc * 4 + 3];
        const float w0b = w[gc * 4 + 4], w1b = w[gc * 4 + 5], w2b = w[gc * 4 + 6], w3b = w[gc * 4 + 7];
        const float bsa = bias[gc], bsb = bias[gc + 1];
        float ya0 = 0.f, ya1 = 0.f, ya2 = 0.f, yb0 = 0.f, yb1 = 0.f, yb2 = 0.f;
        if (j > 0) {
#pragma unroll
            for (int i = 0; i < 3; ++i) {
                uint u = *(const uint*)(src + (size_t)(b * TSEQ + t0 - 3 + i) * HID_ + gc);
                const float lo = bf2f((ushort)u), hi = bf2f((ushort)(u >> 16));
                if (i == 0) { ya0 = lo; yb0 = hi; }
                else if (i == 1) { ya1 = lo; yb1 = hi; }
                else { ya2 = lo; yb2 = hi; }
            }
        }
#pragma unroll 4
        for (int tl = 0; tl < 64; ++tl) {
            uint u = *(const uint*)(src + (size_t)(b * TSEQ + t0 + tl) * HID_ + gc);
            const float x0 = bf2f((ushort)u), x1 = bf2f((ushort)(u >> 16));
            float a0 = fmaf(w0a, ya0, fmaf(w1a, ya1, fmaf(w2a, ya2, fmaf(w3a, x0, bsa))));
            float a1 = fmaf(w0b, yb0, fmaf(w1b, yb1, fmaf(w2b, yb2, fmaf(w3b, x1, bsb))));
            const float s0 = a0 * sig_(a0) * scale;
            const float s1 = a1 * sig_(a1) * scale;
            if (z == 0)      *(uint*)(Qb + tl * KSTR + c2) = pk2(s0, s1);
            else if (z == 1) *(uint*)(Kb + tl * KSTR + c2) = pk2(s0, s1);
            else {
                Vl[(c2 + 0) * 72 + tl] = f2bf(s0);
                Vl[(c2 + 1) * 72 + tl] = f2bf(s1);
            }
            ya0 = ya1; ya1 = ya2; ya2 = x0;
            yb0 = yb1; yb1 = yb2; yb2 = x1;
        }
    }
    __syncthreads();

    // ---- Phase B: grams -> Ef (f32 LDS) + Gl (bf16 LDS)
    const int wv2 = tid >> 6, l = tid & 63, l15 = l & 15, lq = l >> 4;
    const int k8o = lq * 8;
    f32x4 accK[4], accQ4[4];
#pragma unroll
    for (int jx = 0; jx < 4; ++jx) {
        accK[jx] = f32x4{0.f, 0.f, 0.f, 0.f};
        accQ4[jx] = f32x4{0.f, 0.f, 0.f, 0.f};
    }
#pragma unroll
    for (int kk = 0; kk < 4; ++kk) {
        short8 aK = *(const short8*)(Kb + (wv2 * 16 + l15) * KSTR + kk * 32 + k8o);
        short8 aQ = *(const short8*)(Qb + (wv2 * 16 + l15) * KSTR + kk * 32 + k8o);
#pragma unroll
        for (int js = 0; js < 4; ++js) {
            short8 bK = *(const short8*)(Kb + (js * 16 + l15) * KSTR + kk * 32 + k8o);
            accK[js]  = MFMA(aK, bK, accK[js], 0, 0, 0);
            accQ4[js] = MFMA(aQ, bK, accQ4[js], 0, 0, 0);
        }
    }
#pragma unroll
    for (int js = 0; js < 4; ++js) {
#pragma unroll
        for (int r = 0; r < 4; ++r) {
            const int t = wv2 * 16 + lq * 4 + r;
            const int s = js * 16 + l15;
            const float cp = (t > 0) ? cums[t - 1] : 0.f;
            Ef[t * ESTR + s] = (s < t) ? __expf(cp - cums[s]) * accK[js][r] : 0.f;
            const float gv = (s <= t) ? __expf(cums[t] - cums[s]) * accQ4[js][r] : 0.f;
            Gl[t * 64 + s] = f2bf(gv);
        }
    }
    __syncthreads();

    // ---- Phase C: wave 0 LDS M-solve + Mc dump; waves 1-3 coalesced dumps
    const size_t go = (size_t)cid * 8192;
    if (wv2 == 0) {
        const int s = l;                 // lane = column
        for (int r = 0; r < 64; ++r) Mf[r * ESTR + s] = 0.f;
        Mf[s * ESTR + s] = bv2[s];
        for (int t = 1; t < 64; ++t) {
            float s0 = 0.f, s1 = 0.f;
            int r = 0;
            for (; r + 1 < t; r += 2) {
                s0 = fmaf(Ef[t * ESTR + r],     Mf[r * ESTR + s],       s0);
                s1 = fmaf(Ef[t * ESTR + r + 1], Mf[(r + 1) * ESTR + s], s1);
            }
            if (r < t) s0 = fmaf(Ef[t * ESTR + r], Mf[r * ESTR + s], s0);
            if (s < t) Mf[t * ESTR + s] = -bv2[t] * (s0 + s1);
        }
        ushort* Mc = Mg + (size_t)cid * 4096;
#pragma unroll
        for (int r = 0; r < 64; ++r)      // row r: 64 lanes = 128B coalesced
            Mc[r * 64 + s] = f2bf(Mf[r * ESTR + s]);
    } else {
        const int st = tid - 64;          // 0..191
        ushort* Gc = Gg + (size_t)cid * 4096;
        for (int i = st; i < 1024; i += 192) {
            const int row = i >> 4, col = (i & 15) * 8;
            *(uint4*)(Kst + go + i * 8) = *(const uint4*)(Kb + row * KSTR + col);
            *(uint4*)(Qst + go + i * 8) = *(const uint4*)(Qb + row * KSTR + col);
        }
        for (int i = st; i < 512; i += 192)      // Gl -> Gc coalesced (512 u4)
            *(uint4*)(Gc + i * 8) = *(const uint4*)(Gl + i * 8);
        for (int i = st; i < 1024; i += 192) {
            const int dv = i >> 3, tq = (i & 7) * 8;
            *(uint4*)(VstT + go + dv * 64 + tq) = *(const uint4*)(Vl + dv * 72 + tq);
            const int dk = i >> 3, tt = (i & 7) * 8;
            ushort tmp[8];
#pragma unroll
            for (int e = 0; e < 8; ++e)
                tmp[e] = f2bf(bf2f(Kb[(tt + e) * KSTR + dk]) * cv_s[tt + e]);
            *(uint4*)(KTst + go + dk * 64 + tt) = *(uint4*)tmp;
        }
    }
}

// ===== kernel S (serial): swapped-operand chain; single-buffer staging, =====
// 2 barriers/chunk (verified 60us structure from R14; dbuf variant regressed).
__global__ __launch_bounds__(256)
void k_scan2(const ushort* __restrict__ Kst, const ushort* __restrict__ KTst,
             const ushort* __restrict__ VstT, const ushort* __restrict__ Mg,
             const float* __restrict__ pug, const float* __restrict__ dtg,
             ushort* __restrict__ Sst, ushort* __restrict__ Wst)
{
    const int blk = blockIdx.x;          // bh*2 + half
    const int bh = blk >> 1, half = blk & 1;
    const int tid = threadIdx.x;
    const int wv = tid >> 6, l = tid & 63, l15 = l & 15, lq = l >> 4;
    const int k8o = lq * 8;
    const int dvw = wv * 16;

    __shared__ ushort Kb[64 * KSTR];
    __shared__ ushort KTb[128 * 72];
    __shared__ ushort Mb[64 * 72];
    __shared__ ushort Vb[64 * 72];
    __shared__ ushort Shb[64 * KSTR], Slb[64 * KSTR];
    __shared__ ushort Yb[64 * 72], Wb[64 * 72];
    __shared__ float puv[64], dts[1];

    f32x4 accS[8];
#pragma unroll
    for (int m = 0; m < 8; ++m) accS[m] = f32x4{0.f, 0.f, 0.f, 0.f};

    uint4 rk[4], rkt[4], rm[2], rv[2];
    float rpu = 0.f, rdt = 0.f;

    auto LOADC = [&](int cc) {
        const int cid = bh * 16 + cc;
        const size_t go = (size_t)cid * 8192;
#pragma unroll
        for (int jx = 0; jx < 4; ++jx) {
            rk[jx]  = *(const uint4*)(Kst  + go + (tid + jx * 256) * 8);
            rkt[jx] = *(const uint4*)(KTst + go + (tid + jx * 256) * 8);
        }
#pragma unroll
        for (int jx = 0; jx < 2; ++jx) {
            rm[jx] = *(const uint4*)(Mg + (size_t)cid * 4096 + (tid + jx * 256) * 8);
            rv[jx] = *(const uint4*)(VstT + go + half * 4096 + (tid + jx * 256) * 8);
        }
        if (tid < 64) {
            rpu = pug[cid * 64 + tid];
            if (tid == 0) rdt = dtg[cid];
        }
    };
    auto WRITEC = [&]() {
#pragma unroll
        for (int jx = 0; jx < 4; ++jx) {
            const int i16 = tid + jx * 256;
            *(uint4*)(Kb  + (i16 >> 4) * KSTR + (i16 & 15) * 8) = rk[jx];
            *(uint4*)(KTb + (i16 >> 3) * 72   + (i16 & 7) * 8)  = rkt[jx];
        }
#pragma unroll
        for (int jx = 0; jx < 2; ++jx) {
            const int i8 = tid + jx * 256;
            *(uint4*)(Mb + (i8 >> 3) * 72 + (i8 & 7) * 8) = rm[jx];
            *(uint4*)(Vb + (i8 >> 3) * 72 + (i8 & 7) * 8) = rv[jx];
        }
        if (tid < 64) {
            puv[tid] = rpu;
            if (tid == 0) dts[0] = rdt;
        }
    };

    LOADC(0); WRITEC();
    __syncthreads();

    for (int c = 0; c < NCK; ++c) {
        if (c + 1 < NCK) LOADC(c + 1);       // in flight through compute

        // ---- B: state (S^T acc) -> Shb/Slb [dv][dk] via b64 writes
#pragma unroll
        for (int m = 0; m < 8; ++m) {
            ushort h4[4], l4v[4];
#pragma unroll
            for (int r = 0; r < 4; ++r) {
                const float sv = accS[m][r];
                const ushort hi = f2bf(sv);
                h4[r] = hi;
                l4v[r] = f2bf(sv - bf2f(hi));
            }
            *(uint2*)(Shb + (dvw + l15) * KSTR + m * 16 + lq * 4) = *(uint2*)h4;
            *(uint2*)(Slb + (dvw + l15) * KSTR + m * 16 + lq * 4) = *(uint2*)l4v;
        }
        // ---- C': U^T = K.S^T (compensated)
        f32x4 accU[4];
#pragma unroll
        for (int jj = 0; jj < 4; ++jj) accU[jj] = f32x4{0.f, 0.f, 0.f, 0.f};
#pragma unroll
        for (int kk = 0; kk < 4; ++kk) {
            short8 sh = *(const short8*)(Shb + (dvw + l15) * KSTR + kk * 32 + k8o);
            short8 sl = *(const short8*)(Slb + (dvw + l15) * KSTR + kk * 32 + k8o);
#pragma unroll
            for (int jj = 0; jj < 4; ++jj) {
                short8 ka = *(const short8*)(Kb + (jj * 16 + l15) * KSTR + kk * 32 + k8o);
                accU[jj] = MFMA(ka, sh, accU[jj], 0, 0, 0);
                accU[jj] = MFMA(ka, sl, accU[jj], 0, 0, 0);
            }
        }
        // ---- D': Y[dv][t] = V - pu (.) U (lane-local b64)
#pragma unroll
        for (int jj = 0; jj < 4; ++jj) {
            float pu4[4];
            *(float4*)pu4 = *(const float4*)(puv + jj * 16 + lq * 4);
            ushort v4[4];
            *(uint2*)v4 = *(const uint2*)(Vb + (dvw + l15) * 72 + jj * 16 + lq * 4);
            ushort y4[4];
#pragma unroll
            for (int r = 0; r < 4; ++r)
                y4[r] = f2bf(bf2f(v4[r]) - pu4[r] * accU[jj][r]);
            *(uint2*)(Yb + (dvw + l15) * 72 + jj * 16 + lq * 4) = *(uint2*)y4;
        }
        // ---- E'': W^T = M.Y
        f32x4 accW[4];
#pragma unroll
        for (int jj = 0; jj < 4; ++jj) accW[jj] = f32x4{0.f, 0.f, 0.f, 0.f};
#pragma unroll
        for (int kk = 0; kk < 2; ++kk) {
            short8 yb = *(const short8*)(Yb + (dvw + l15) * 72 + kk * 32 + k8o);
#pragma unroll
            for (int jj = 0; jj < 4; ++jj) {
                short8 mf = *(const short8*)(Mb + (jj * 16 + l15) * 72 + kk * 32 + k8o);
                accW[jj] = MFMA(mf, yb, accW[jj], 0, 0, 0);
            }
        }
#pragma unroll
        for (int jj = 0; jj < 4; ++jj) {
            ushort w4[4];
#pragma unroll
            for (int r = 0; r < 4; ++r)
                w4[r] = f2bf(accW[jj][r]);
            *(uint2*)(Wb + (dvw + l15) * 72 + jj * 16 + lq * 4) = *(uint2*)w4;
        }
        // ---- G: S^T = dtot.S^T + KTc.W   (KT pre-scaled by cv)
        const float dt = dts[0];
#pragma unroll
        for (int m = 0; m < 8; ++m)
#pragma unroll
            for (int r = 0; r < 4; ++r) accS[m][r] *= dt;
#pragma unroll
        for (int kk = 0; kk < 2; ++kk) {
            short8 wc = *(const short8*)(Wb + (dvw + l15) * 72 + kk * 32 + k8o);
#pragma unroll
            for (int m = 0; m < 8; ++m) {
                short8 kt = *(const short8*)(KTb + (m * 16 + l15) * 72 + kk * 32 + k8o);
                accS[m] = MFMA(kt, wc, accS[m], 0, 0, 0);
            }
        }
        // ---- dumps (wave-local rows of Shb/Wb)
        {
            const int cid = bh * 16 + c;
#pragma unroll
            for (int jx = 0; jx < 4; ++jx) {
                const int idx = l + jx * 64;
                const int dvo = idx >> 4, ko = (idx & 15) * 8;
                *(uint4*)(Sst + (size_t)cid * 16384 +
                          (half * 64 + dvw + dvo) * 128 + ko) =
                    *(const uint4*)(Shb + (dvw + dvo) * KSTR + ko);
            }
#pragma unroll
            for (int jx = 0; jx < 2; ++jx) {
                const int idx = l + jx * 64;
                const int dvo = idx >> 3, t8 = (idx & 7) * 8;
                *(uint4*)(Wst + (size_t)cid * 8192 +
                          (half * 64 + dvw + dvo) * 64 + t8) =
                    *(const uint4*)(Wb + (dvw + dvo) * 72 + t8);
            }
        }
        __syncthreads();        // all reads of shared bufs done
        if (c + 1 < NCK) WRITEC();
        __syncthreads();        // staged chunk visible
    }
}

// ===== kernel O (parallel): O = po (.) S.Q^T + G.W, fused LayerNorm + gate ====
__global__ __launch_bounds__(256)
void k_out(const ushort* __restrict__ Sst, const ushort* __restrict__ Qst,
           const ushort* __restrict__ Gg, const ushort* __restrict__ Wst,
           const float* __restrict__ pog, const ushort* __restrict__ gb_,
           const float* __restrict__ lng, const float* __restrict__ lnb,
           ushort* __restrict__ ogb)
{
    const int cid = blockIdx.x;
    const int bh = cid >> 4, c = cid & 15;
    const int b = bh >> 3, h = bh & 7;
    const int t0 = c * LCH;
    const int tid = threadIdx.x;
    const int wv = tid >> 6, l = tid & 63, l15 = l & 15, lq = l >> 4;
    const int k8o = lq * 8;

    __shared__ ushort Sb[128 * KSTR];
    __shared__ ushort Qb[64 * KSTR];
    __shared__ ushort Gb[64 * 72];
    __shared__ ushort Wqb[128 * 72];
    __shared__ float  Ot[64 * 132];
    __shared__ float  pov[64];

#pragma unroll
    for (int jx = 0; jx < 8; ++jx) {
        const int i16 = tid + jx * 256;
        *(uint4*)(Sb + (i16 >> 4) * KSTR + (i16 & 15) * 8) =
            *(const uint4*)(Sst + (size_t)cid * 16384 + i16 * 8);
    }
#pragma unroll
    for (int jx = 0; jx < 4; ++jx) {
        const int i16 = tid + jx * 256;
        *(uint4*)(Qb + (i16 >> 4) * KSTR + (i16 & 15) * 8) =
            *(const uint4*)(Qst + (size_t)cid * 8192 + i16 * 8);
        *(uint4*)(Wqb + (i16 >> 3) * 72 + (i16 & 7) * 8) =
            *(const uint4*)(Wst + (size_t)cid * 8192 + i16 * 8);
    }
#pragma unroll
    for (int jx = 0; jx < 2; ++jx) {
        const int i8 = tid + jx * 256;
        *(uint4*)(Gb + (i8 >> 3) * 72 + (i8 & 7) * 8) =
            *(const uint4*)(Gg + (size_t)cid * 4096 + i8 * 8);
    }
    if (tid < 64) pov[tid] = pog[cid * 64 + tid];
    __syncthreads();

#pragma unroll
    for (int i = 0; i < 2; ++i) {
        const int dvt = wv * 2 + i;
        f32x4 acc[4], acg[4];
#pragma unroll
        for (int jj = 0; jj < 4; ++jj) {
            acc[jj] = f32x4{0.f, 0.f, 0.f, 0.f};
            acg[jj] = f32x4{0.f, 0.f, 0.f, 0.f};
        }
#pragma unroll
        for (int kk = 0; kk < 4; ++kk) {
            short8 sa = *(const short8*)(Sb + (dvt * 16 + l15) * KSTR + kk * 32 + k8o);
#pragma unroll
            for (int jj = 0; jj < 4; ++jj) {
                short8 qb = *(const short8*)(Qb + (jj * 16 + l15) * KSTR + kk * 32 + k8o);
                acc[jj] = MFMA(sa, qb, acc[jj], 0, 0, 0);
            }
        }
#pragma unroll
        for (int kk = 0; kk < 2; ++kk) {
            short8 wa = *(const short8*)(Wqb + (dvt * 16 + l15) * 72 + kk * 32 + k8o);
#pragma unroll
            for (int jj = 0; jj < 4; ++jj) {
                short8 gb = *(const short8*)(Gb + (jj * 16 + l15) * 72 + kk * 32 + k8o);
                acg[jj] = MFMA(wa, gb, acg[jj], 0, 0, 0);
            }
        }
#pragma unroll
        for (int jj = 0; jj < 4; ++jj) {
            const int t = jj * 16 + l15;
            const float po = pov[t];
            float4 o4;
            o4.x = po * acc[jj][0] + acg[jj][0];
            o4.y = po * acc[jj][1] + acg[jj][1];
            o4.z = po * acc[jj][2] + acg[jj][2];
            o4.w = po * acc[jj][3] + acg[jj][3];
            *(float4*)(Ot + t * 132 + dvt * 16 + lq * 4) = o4;
        }
    }
    __syncthreads();

    const int d = l * 2;
    const float lg0 = lng[d], lg1 = lng[d + 1];
    const float lb0 = lnb[d], lb1 = lnb[d + 1];
    const size_t btbase = (size_t)b * TSEQ + t0 + wv * 16;
#pragma unroll 1
    for (int rr = 0; rr < 16; ++rr) {
        const int t = wv * 16 + rr;
        float2 xv = *(const float2*)(Ot + t * 132 + d);
        float s = xv.x + xv.y;
#pragma unroll
        for (int m = 32; m; m >>= 1) s += __shfl_xor(s, m);
        const float mu = s * (1.f / 128.f);
        const float d0 = xv.x - mu, d1 = xv.y - mu;
        float v = d0 * d0 + d1 * d1;
#pragma unroll
        for (int m = 32; m; m >>= 1) v += __shfl_xor(v, m);
        const float inv = rsqrtf(v * (1.f / 128.f) + 1e-5f);
        const uint gu = *(const uint*)(gb_ + (btbase + rr) * HID_ + h * DV + d);
        const float g0 = sig_(bf2f((ushort)gu)), g1 = sig_(bf2f((ushort)(gu >> 16)));
        const float y0 = (d0 * inv * lg0 + lb0) * g0;
        const float y1 = (d1 * inv * lg1 + lb1) * g1;
        *(uint*)(ogb + (btbase + rr) * HID_ + h * DV + d) = pk2(y0, y1);
    }
}

extern "C" void kernel_launch(void* const* d_in, const int* in_sizes, int n_in,
                              void* d_out, int out_size, void* d_ws, size_t ws_size,
                              hipStream_t stream)
{
    const float* x   = (const float*)d_in[0];
    const float* Wq  = (const float*)d_in[1];
    const float* Wk  = (const float*)d_in[2];
    const float* Wv  = (const float*)d_in[3];
    const float* cqw = (const float*)d_in[4];
    const float* cqb = (const float*)d_in[5];
    const float* ckw = (const float*)d_in[6];
    const float* ckb = (const float*)d_in[7];
    const float* cvw = (const float*)d_in[8];
    const float* cvb = (const float*)d_in[9];
    const float* Wa  = (const float*)d_in[10];
    const float* ba  = (const float*)d_in[11];
    const float* Wb  = (const float*)d_in[12];
    const float* bb  = (const float*)d_in[13];
    const float* Wg  = (const float*)d_in[14];
    const float* Wo  = (const float*)d_in[15];
    const float* lng = (const float*)d_in[16];
    const float* lnb = (const float*)d_in[17];
    float* out = (float*)d_out;
    float* ws  = (float*)d_ws;

    ushort* qb_ = (ushort*)ws;
    ushort* kb_ = qb_ + (size_t)SZf;
    ushort* vb_ = qb_ + (size_t)2 * SZf;
    ushort* gb_ = qb_ + (size_t)3 * SZf;

    ushort* ogb  = (ushort*)(ws + 2 * (size_t)SZf);           // 4MB (lo)
    ushort* VstT = ogb + (size_t)2 * 1024 * 1024;             // 4MB (hi)
    ushort* WoT  = (ushort*)(ws + 3 * (size_t)SZf);           // 2MB (free region)
    float*  o_buf = ws + 4 * (size_t)SZf;
    ushort* WT4  = (ushort*)o_buf;                            // 8MB, dead after gemm4
    ushort* Sst  = (ushort*)o_buf;                            // 8MB (scan out)
    float* aT  = ws + 5 * (size_t)SZf;
    float* bT  = aT + 16 * TSEQ;
    float* pug = bT + 16 * TSEQ;
    float* pog = pug + 256 * 64;
    float* dtg = pog + 256 * 64;

    float*  tail = ws + 5 * (size_t)SZf + 131072;
    ushort* Kst  = (ushort*)tail;                             // 4MB
    ushort* Qst  = Kst + (size_t)256 * 8192;                  // 4MB
    ushort* xbf  = Qst + (size_t)256 * 8192;                  // 4MB; dead after gemm4
    ushort* KTst = xbf;                                       // reuse

    ushort* Mg  = (ushort*)out;                               // 2MB
    ushort* Gg  = Mg + (size_t)256 * 4096;                    // 2MB
    ushort* Wst = Gg + (size_t)256 * 4096;                    // 4MB

    k_x2bf<<<1024, 256, 0, stream>>>(x, xbf);
    k_wT<<<dim3(16, 16, 5), 256, 0, stream>>>(Wq, Wk, Wv, Wg, Wo, WT4, WoT);
    k_gemm4<<<dim3(8, 16, 4), 256, 0, stream>>>(xbf, WT4, qb_);
    k_ab<<<512, 256, 0, stream>>>(x, Wa, ba, Wb, bb, aT, bT);
    k_convprep<<<256, 256, 0, stream>>>(qb_, kb_, vb_,
                                        cqw, cqb, ckw, ckb, cvw, cvb,
                                        aT, bT, Kst, Qst, VstT, KTst,
                                        Mg, Gg, pug, pog, dtg);
    k_scan2<<<32, 256, 0, stream>>>(Kst, KTst, VstT, Mg, pug, dtg, Sst, Wst);
    k_out<<<256, 256, 0, stream>>>(Sst, Qst, Gg, Wst, pog, gb_, lng, lnb, ogb);
    k_gemm1<<<dim3(8, 16), 256, 0, stream>>>(ogb, WoT, out);
}